// Round 1
// baseline (741.373 us; speedup 1.0000x reference)
//
#include <hip/hip_runtime.h>

static constexpr int NN = 50000;      // nodes
static constexpr int NE = 800000;     // edges
static constexpr int DEMB = 512;
static constexpr int QKV_OUT = 1536;  // (2*64+64)*8

typedef _Float16 half8 __attribute__((ext_vector_type(8)));
typedef _Float16 half4 __attribute__((ext_vector_type(4)));
typedef float floatx4 __attribute__((ext_vector_type(4)));

// ---------------- workspace layout (bytes) ----------------
static constexpr size_t OFF_QKV  = 0;                    // N*1536 f16 = 153,600,000
static constexpr size_t OFF_MSG  = 153600000;            // N*512 f16  =  51,200,000
static constexpr size_t OFF_SRT  = 204800000;            // E i32      =   3,200,000
static constexpr size_t OFF_DEG  = 208000000;            // N i32      =     200,000
static constexpr size_t OFF_OFFA = 208200000;            // (N+1) i32  =     200,004
static constexpr size_t OFF_CUR  = 208400064;            // N i32      =     200,000
static constexpr size_t OFF_FLAG = 208600064;            // 1 i32

// ---------------- edge dtype detection (int32 vs int64) ----------------
__global__ __launch_bounds__(64)
void k_detect64(const void* __restrict__ edge, int* __restrict__ flag) {
  if (threadIdx.x == 0) {
    const int* p = (const int*)edge;
    int is64 = 1;
    for (int i = 0; i < 16; ++i) if (p[2 * i + 1] != 0) is64 = 0;
    *flag = is64;
  }
}

__device__ __forceinline__ int edge_at(const void* edge, int row, int e, int is64) {
  if (is64) return (int)((const long long*)edge)[(size_t)row * NE + e];
  return ((const int*)edge)[(size_t)row * NE + e];
}

// ---------------- CSR build ----------------
__global__ __launch_bounds__(256)
void k_histo(const void* __restrict__ edge, const int* __restrict__ flag,
             int* __restrict__ deg) {
  int e = blockIdx.x * 256 + threadIdx.x;
  if (e < NE) {
    int r = edge_at(edge, 1, e, *flag);
    atomicAdd(&deg[r], 1);
  }
}

__global__ __launch_bounds__(1024)
void k_scan(const int* __restrict__ deg, int* __restrict__ off,
            int* __restrict__ cur, int n) {
  __shared__ int sums[1024];
  int tid = threadIdx.x;
  int per = (n + 1023) >> 10;
  int start = tid * per;
  int end = start + per; if (end > n) end = n;
  int s = 0;
  for (int i = start; i < end; ++i) s += deg[i];
  sums[tid] = s;
  __syncthreads();
  for (int d = 1; d < 1024; d <<= 1) {
    int v = (tid >= d) ? sums[tid - d] : 0;
    __syncthreads();
    sums[tid] += v;
    __syncthreads();
  }
  int run = (tid == 0) ? 0 : sums[tid - 1];
  for (int i = start; i < end; ++i) {
    off[i] = run; cur[i] = run; run += deg[i];
  }
  if (tid == 0) off[n] = sums[1023];
}

__global__ __launch_bounds__(256)
void k_scatter(const void* __restrict__ edge, const int* __restrict__ flag,
               int* __restrict__ cur, int* __restrict__ srt) {
  int e = blockIdx.x * 256 + threadIdx.x;
  if (e < NE) {
    int is64 = *flag;
    int r = edge_at(edge, 1, e, is64);
    int s = edge_at(edge, 0, e, is64);
    int pos = atomicAdd(&cur[r], 1);
    srt[pos] = s;
  }
}

// ---------------- GEMM (NT): C[m,n] = sum_k A[m,k]*B[n,k] + bias[n] ----------------
// A: [M,K] f32 or f16 row-major; B: [N,K] f32 row-major; C: f16 or f32.
// 128x128 tile, BK=32, 4 waves (2x2 of 64x64), mfma_f32_16x16x32_f16.
template<bool A_HALF, bool OUT_HALF>
__global__ __launch_bounds__(256)
void k_gemm_nt(const void* __restrict__ Ap, const float* __restrict__ B,
               const float* __restrict__ bias, void* __restrict__ Cp,
               int M, int N, int K) {
  __shared__ _Float16 As[128][32];
  __shared__ _Float16 Bs[128][32];
  const int tid = threadIdx.x;
  const int m0 = blockIdx.x * 128;
  const int n0 = blockIdx.y * 128;
  const int wid = tid >> 6, lane = tid & 63;
  const int wr = wid >> 1, wc = wid & 1;

  floatx4 acc[4][4];
  #pragma unroll
  for (int i = 0; i < 4; ++i)
    #pragma unroll
    for (int j = 0; j < 4; ++j)
      #pragma unroll
      for (int q = 0; q < 4; ++q) acc[i][j][q] = 0.f;

  const int sr = tid >> 3;        // 0..31
  const int sc = (tid & 7) << 2;  // 0..28 step 4
  const int fr = lane & 15;
  const int fk = (lane >> 4) << 3;

  for (int k0 = 0; k0 < K; k0 += 32) {
    #pragma unroll
    for (int i = 0; i < 4; ++i) {
      int r = i * 32 + sr;
      int gm = m0 + r; gm = gm < M ? gm : M - 1;   // clamp; masked at store
      half4 hv;
      if (A_HALF) {
        hv = *(const half4*)((const _Float16*)Ap + (size_t)gm * K + k0 + sc);
      } else {
        floatx4 v = *(const floatx4*)((const float*)Ap + (size_t)gm * K + k0 + sc);
        #pragma unroll
        for (int q = 0; q < 4; ++q) hv[q] = (_Float16)v[q];
      }
      *(half4*)(&As[r][sc]) = hv;

      int gn = n0 + r;  // N is a multiple of 128 for both GEMMs
      floatx4 w = *(const floatx4*)(B + (size_t)gn * K + k0 + sc);
      half4 wv;
      #pragma unroll
      for (int q = 0; q < 4; ++q) wv[q] = (_Float16)w[q];
      *(half4*)(&Bs[r][sc]) = wv;
    }
    __syncthreads();

    half8 a[4], b[4];
    #pragma unroll
    for (int m = 0; m < 4; ++m)
      a[m] = *(const half8*)(&As[wr * 64 + m * 16 + fr][fk]);
    #pragma unroll
    for (int n = 0; n < 4; ++n)
      b[n] = *(const half8*)(&Bs[wc * 64 + n * 16 + fr][fk]);
    #pragma unroll
    for (int m = 0; m < 4; ++m)
      #pragma unroll
      for (int n = 0; n < 4; ++n)
        acc[m][n] = __builtin_amdgcn_mfma_f32_16x16x32_f16(a[m], b[n], acc[m][n], 0, 0, 0);
    __syncthreads();
  }

  // epilogue: C/D layout col=lane&15, row=(lane>>4)*4+q  [m89/m91 verified]
  const int fq = (lane >> 4) << 2;
  #pragma unroll
  for (int m = 0; m < 4; ++m) {
    #pragma unroll
    for (int n = 0; n < 4; ++n) {
      int gn = n0 + wc * 64 + n * 16 + fr;
      float bv = bias[gn];
      #pragma unroll
      for (int q = 0; q < 4; ++q) {
        int gm = m0 + wr * 64 + m * 16 + fq + q;
        if (gm < M) {
          float val = acc[m][n][q] + bv;
          if (OUT_HALF) ((_Float16*)Cp)[(size_t)gm * N + gn] = (_Float16)val;
          else          ((float*)Cp)[(size_t)gm * N + gn] = val;
        }
      }
    }
  }
}

// ---------------- attention aggregation: one wave per receiver ----------------
// qkv row layout: [0,512)=Q, [512,1024)=K, [1024,1536)=V ; head h dims h*64..h*64+63
__global__ __launch_bounds__(256)
void k_attn(const _Float16* __restrict__ qkv, const int* __restrict__ off,
            const int* __restrict__ srt, _Float16* __restrict__ msg) {
  int r = blockIdx.x * 4 + (threadIdx.x >> 6);
  if (r >= NN) return;
  int lane = threadIdx.x & 63;
  int h = lane >> 3, j = lane & 7;
  int qoff = h * 64 + j * 8;     // this lane's 8 dims of head h

  const _Float16* qrow = qkv + (size_t)r * QKV_OUT;
  half8 qh = *(const half8*)(qrow + qoff);
  float q[8];
  #pragma unroll
  for (int i = 0; i < 8; ++i) q[i] = (float)qh[i] * 0.125f;  // 1/sqrt(64)

  float denom = 0.f;
  float acc[8];
  #pragma unroll
  for (int i = 0; i < 8; ++i) acc[i] = 0.f;

  int e0 = off[r], e1 = off[r + 1];
  for (int e = e0; e < e1; ++e) {
    int s = srt[e];
    const _Float16* srow = qkv + (size_t)s * QKV_OUT;
    half8 kh = *(const half8*)(srow + 512 + qoff);
    half8 vh = *(const half8*)(srow + 1024 + qoff);
    float p = 0.f;
    #pragma unroll
    for (int i = 0; i < 8; ++i) p += q[i] * (float)kh[i];
    p += __shfl_xor(p, 1);
    p += __shfl_xor(p, 2);
    p += __shfl_xor(p, 4);
    float w = __expf(p);           // exact softmax sans max-shift (scores ~N(0,1))
    denom += w;
    #pragma unroll
    for (int i = 0; i < 8; ++i) acc[i] += w * (float)vh[i];
  }
  float inv = denom > 0.f ? 1.f / denom : 0.f;
  half8 oh;
  #pragma unroll
  for (int i = 0; i < 8; ++i) oh[i] = (_Float16)(acc[i] * inv);
  *(half8*)(msg + (size_t)r * 512 + qoff) = oh;
}

// ---------------- launcher ----------------
extern "C" void kernel_launch(void* const* d_in, const int* in_sizes, int n_in,
                              void* d_out, int out_size, void* d_ws, size_t ws_size,
                              hipStream_t stream) {
  const float* x     = (const float*)d_in[0];
  const void*  edge  = d_in[1];
  const float* W_qkv = (const float*)d_in[2];
  const float* b_qkv = (const float*)d_in[3];
  const float* W_ff  = (const float*)d_in[4];
  const float* b_ff  = (const float*)d_in[5];
  float* out = (float*)d_out;

  char* ws = (char*)d_ws;
  _Float16* qkvb = (_Float16*)(ws + OFF_QKV);
  _Float16* msgb = (_Float16*)(ws + OFF_MSG);
  int* srt  = (int*)(ws + OFF_SRT);
  int* deg  = (int*)(ws + OFF_DEG);
  int* offa = (int*)(ws + OFF_OFFA);
  int* cur  = (int*)(ws + OFF_CUR);
  int* flag = (int*)(ws + OFF_FLAG);

  hipMemsetAsync(deg, 0, NN * sizeof(int), stream);
  k_detect64<<<1, 64, 0, stream>>>(edge, flag);

  // QKV projection: [N,512] x [1536,512]^T -> f16 [N,1536]
  k_gemm_nt<false, true><<<dim3(391, 12), 256, 0, stream>>>(
      x, W_qkv, b_qkv, qkvb, NN, QKV_OUT, DEMB);

  k_histo<<<(NE + 255) / 256, 256, 0, stream>>>(edge, flag, deg);
  k_scan<<<1, 1024, 0, stream>>>(deg, offa, cur, NN);
  k_scatter<<<(NE + 255) / 256, 256, 0, stream>>>(edge, flag, cur, srt);

  // per-receiver online softmax + weighted V aggregation -> f16 [N,512]
  k_attn<<<(NN + 3) / 4, 256, 0, stream>>>(qkvb, offa, srt, msgb);

  // output projection: [N,512] x [512,512]^T -> f32 d_out
  k_gemm_nt<true, false><<<dim3(391, 4), 256, 0, stream>>>(
      msgb, W_ff, b_ff, out, NN, DEMB, DEMB);
}

// Round 2
// 692.180 us; speedup vs baseline: 1.0711x; 1.0711x over previous
//
#include <hip/hip_runtime.h>

static constexpr int NN = 50000;      // nodes
static constexpr int NE = 800000;     // edges
static constexpr int DEMB = 512;
static constexpr int QKV_OUT = 1536;  // (2*64+64)*8

typedef _Float16 half8 __attribute__((ext_vector_type(8)));
typedef float floatx4 __attribute__((ext_vector_type(4)));

// ---------------- workspace layout (bytes) ----------------
static constexpr size_t OFF_QKV  = 0;                    // N*1536 f16 = 153,600,000
static constexpr size_t OFF_MSG  = 153600000;            // N*512 f16  =  51,200,000 (aliases xh)
static constexpr size_t OFF_SRT  = 204800000;            // E i32      =   3,200,000
static constexpr size_t OFF_DEG  = 208000000;            // N i32      =     200,000
static constexpr size_t OFF_OFFA = 208200000;            // (N+1) i32
static constexpr size_t OFF_CUR  = 208400064;            // N i32
static constexpr size_t OFF_FLAG = 208600064;            // 1 i32
static constexpr size_t OFF_WQH  = 208600128;            // 1536*512 f16 = 1,572,864
static constexpr size_t OFF_WFH  = 210172992;            // 512*512 f16  =   524,288

typedef __attribute__((address_space(1))) const void* gas_ptr;
typedef __attribute__((address_space(3))) void* lds_ptr_t;

__device__ __forceinline__ void load_lds16(const void* g, void* l) {
  __builtin_amdgcn_global_load_lds((gas_ptr)g, (lds_ptr_t)l, 16, 0, 0);
}

// ---------------- f32 -> f16 convert ----------------
__global__ __launch_bounds__(256)
void k_cvt(const float* __restrict__ in, _Float16* __restrict__ out, int n8) {
  int i = blockIdx.x * 256 + threadIdx.x;
  if (i < n8) {
    floatx4 a = *(const floatx4*)(in + (size_t)i * 8);
    floatx4 b = *(const floatx4*)(in + (size_t)i * 8 + 4);
    half8 h;
    #pragma unroll
    for (int q = 0; q < 4; ++q) { h[q] = (_Float16)a[q]; h[q + 4] = (_Float16)b[q]; }
    *(half8*)(out + (size_t)i * 8) = h;
  }
}

// ---------------- edge dtype detection (int32 vs int64) ----------------
__global__ __launch_bounds__(64)
void k_detect64(const void* __restrict__ edge, int* __restrict__ flag) {
  if (threadIdx.x == 0) {
    const int* p = (const int*)edge;
    int is64 = 1;
    for (int i = 0; i < 16; ++i) if (p[2 * i + 1] != 0) is64 = 0;
    *flag = is64;
  }
}

__device__ __forceinline__ int edge_at(const void* edge, int row, int e, int is64) {
  if (is64) return (int)((const long long*)edge)[(size_t)row * NE + e];
  return ((const int*)edge)[(size_t)row * NE + e];
}

// ---------------- CSR build ----------------
__global__ __launch_bounds__(256)
void k_histo(const void* __restrict__ edge, const int* __restrict__ flag,
             int* __restrict__ deg) {
  int e = blockIdx.x * 256 + threadIdx.x;
  if (e < NE) {
    int r = edge_at(edge, 1, e, *flag);
    atomicAdd(&deg[r], 1);
  }
}

__global__ __launch_bounds__(1024)
void k_scan(const int* __restrict__ deg, int* __restrict__ off,
            int* __restrict__ cur, int n) {
  __shared__ int sums[1024];
  int tid = threadIdx.x;
  int per = (n + 1023) >> 10;
  int start = tid * per;
  int end = start + per; if (end > n) end = n;
  int s = 0;
  for (int i = start; i < end; ++i) s += deg[i];
  sums[tid] = s;
  __syncthreads();
  for (int d = 1; d < 1024; d <<= 1) {
    int v = (tid >= d) ? sums[tid - d] : 0;
    __syncthreads();
    sums[tid] += v;
    __syncthreads();
  }
  int run = (tid == 0) ? 0 : sums[tid - 1];
  for (int i = start; i < end; ++i) {
    off[i] = run; cur[i] = run; run += deg[i];
  }
  if (tid == 0) off[n] = sums[1023];
}

__global__ __launch_bounds__(256)
void k_scatter(const void* __restrict__ edge, const int* __restrict__ flag,
               int* __restrict__ cur, int* __restrict__ srt) {
  int e = blockIdx.x * 256 + threadIdx.x;
  if (e < NE) {
    int is64 = *flag;
    int r = edge_at(edge, 1, e, is64);
    int s = edge_at(edge, 0, e, is64);
    int pos = atomicAdd(&cur[r], 1);
    srt[pos] = s;
  }
}

// ---------------- GEMM (NT): C[m,n] = sum_k A[m,k]*B[n,k] + bias[n] ----------------
// A: [M,K] f16 row-major; B: [N,K] f16 row-major; C: f16 or f32.
// 128x128 tile, BK=32, global_load_lds width=16 staging (m97 structure).
// LDS layout: [128 rows][4 slots of 16B], slot swizzled: stored slot s holds
// global chunk s ^ (row&3). Source pre-swizzle + read-side swizzle (rule #21).
template<bool OUT_HALF>
__global__ __launch_bounds__(256)
void k_gemm_nt(const _Float16* __restrict__ Ah, const _Float16* __restrict__ Bh,
               const float* __restrict__ bias, void* __restrict__ Cp,
               int M, int N, int K) {
  __shared__ _Float16 As[128 * 32];
  __shared__ _Float16 Bs[128 * 32];
  const int tid = threadIdx.x;
  const int m0 = blockIdx.x * 128;
  const int n0 = blockIdx.y * 128;
  const int wid = tid >> 6, lane = tid & 63;
  const int wr = wid >> 1, wc = wid & 1;

  floatx4 acc[4][4];
  #pragma unroll
  for (int i = 0; i < 4; ++i)
    #pragma unroll
    for (int j = 0; j < 4; ++j)
      #pragma unroll
      for (int q = 0; q < 4; ++q) acc[i][j][q] = 0.f;

  // staging decomposition: linear byte L = c*4096 + tid*16
  const int srow = tid >> 2;                   // row for c=0 (c=1 adds 64)
  const int sslot = tid & 3;                   // stored slot
  // fragment read indices
  const int fr = lane & 15;
  const int fslot = lane >> 4;                 // 0..3 (16B slots along K)

  // per-row A global clamp (rows >= M clamped to M-1, masked at store)
  int garow0 = m0 + srow;       if (garow0 >= M) garow0 = M - 1;
  int garow1 = m0 + srow + 64;  if (garow1 >= M) garow1 = M - 1;
  const int aslot0 = sslot ^ (srow & 3);       // source chunk (swizzle)
  const int gbrow0 = n0 + srow, gbrow1 = n0 + srow + 64;

  for (int k0 = 0; k0 < K; k0 += 32) {
    // ---- stage A,B tiles: 4 x global_load_lds_dwordx4 per thread-group ----
    load_lds16(Ah + (size_t)garow0 * K + k0 + aslot0 * 8,
               (char*)As + wid * 1024);
    load_lds16(Ah + (size_t)garow1 * K + k0 + aslot0 * 8,
               (char*)As + 4096 + wid * 1024);
    load_lds16(Bh + (size_t)gbrow0 * K + k0 + aslot0 * 8,
               (char*)Bs + wid * 1024);
    load_lds16(Bh + (size_t)gbrow1 * K + k0 + aslot0 * 8,
               (char*)Bs + 4096 + wid * 1024);
    __syncthreads();   // drains vmcnt -> LDS writes visible

    half8 a[4], b[4];
    #pragma unroll
    for (int m = 0; m < 4; ++m) {
      int R = wr * 64 + m * 16 + fr;
      a[m] = *(const half8*)(As + R * 32 + ((fslot ^ (R & 3)) << 3));
    }
    #pragma unroll
    for (int n = 0; n < 4; ++n) {
      int R = wc * 64 + n * 16 + fr;
      b[n] = *(const half8*)(Bs + R * 32 + ((fslot ^ (R & 3)) << 3));
    }
    #pragma unroll
    for (int m = 0; m < 4; ++m)
      #pragma unroll
      for (int n = 0; n < 4; ++n)
        acc[m][n] = __builtin_amdgcn_mfma_f32_16x16x32_f16(a[m], b[n], acc[m][n], 0, 0, 0);
    __syncthreads();   // all reads done before next stage overwrites
  }

  // epilogue: C/D layout col=lane&15, row=(lane>>4)*4+q  [m89/m91 verified]
  const int fq = (lane >> 4) << 2;
  #pragma unroll
  for (int m = 0; m < 4; ++m) {
    #pragma unroll
    for (int n = 0; n < 4; ++n) {
      int gn = n0 + wc * 64 + n * 16 + fr;
      float bv = bias[gn];
      #pragma unroll
      for (int q = 0; q < 4; ++q) {
        int gm = m0 + wr * 64 + m * 16 + fq + q;
        if (gm < M) {
          float val = acc[m][n][q] + bv;
          if (OUT_HALF) ((_Float16*)Cp)[(size_t)gm * N + gn] = (_Float16)val;
          else          ((float*)Cp)[(size_t)gm * N + gn] = val;
        }
      }
    }
  }
}

// ---------------- attention aggregation: one wave per receiver ----------------
// qkv row layout: [0,512)=Q, [512,1024)=K, [1024,1536)=V ; head h dims h*64..h*64+63
__global__ __launch_bounds__(256)
void k_attn(const _Float16* __restrict__ qkv, const int* __restrict__ off,
            const int* __restrict__ srt, _Float16* __restrict__ msg) {
  int r = blockIdx.x * 4 + (threadIdx.x >> 6);
  if (r >= NN) return;
  int lane = threadIdx.x & 63;
  int h = lane >> 3, j = lane & 7;
  int qoff = h * 64 + j * 8;     // this lane's 8 dims of head h

  const _Float16* qrow = qkv + (size_t)r * QKV_OUT;
  half8 qh = *(const half8*)(qrow + qoff);
  float q[8];
  #pragma unroll
  for (int i = 0; i < 8; ++i) q[i] = (float)qh[i] * 0.125f;  // 1/sqrt(64)

  float denom = 0.f;
  float acc[8];
  #pragma unroll
  for (int i = 0; i < 8; ++i) acc[i] = 0.f;

  int e0 = off[r], e1 = off[r + 1];
  // 1-deep software pipeline on the K/V gathers
  int s = (e0 < e1) ? srt[e0] : 0;
  const _Float16* srow = qkv + (size_t)s * QKV_OUT;
  half8 kh = *(const half8*)(srow + 512 + qoff);
  half8 vh = *(const half8*)(srow + 1024 + qoff);
  for (int e = e0; e < e1; ++e) {
    half8 kn = kh, vn = vh;
    if (e + 1 < e1) {
      int s2 = srt[e + 1];
      const _Float16* srow2 = qkv + (size_t)s2 * QKV_OUT;
      kn = *(const half8*)(srow2 + 512 + qoff);
      vn = *(const half8*)(srow2 + 1024 + qoff);
    }
    float p = 0.f;
    #pragma unroll
    for (int i = 0; i < 8; ++i) p += q[i] * (float)kh[i];
    p += __shfl_xor(p, 1);
    p += __shfl_xor(p, 2);
    p += __shfl_xor(p, 4);
    float w = __expf(p);           // exact softmax sans max-shift (scores ~N(0,1))
    denom += w;
    #pragma unroll
    for (int i = 0; i < 8; ++i) acc[i] += w * (float)vh[i];
    kh = kn; vh = vn;
  }
  float inv = denom > 0.f ? 1.f / denom : 0.f;
  half8 oh;
  #pragma unroll
  for (int i = 0; i < 8; ++i) oh[i] = (_Float16)(acc[i] * inv);
  *(half8*)(msg + (size_t)r * 512 + qoff) = oh;
}

// ---------------- launcher ----------------
extern "C" void kernel_launch(void* const* d_in, const int* in_sizes, int n_in,
                              void* d_out, int out_size, void* d_ws, size_t ws_size,
                              hipStream_t stream) {
  const float* x     = (const float*)d_in[0];
  const void*  edge  = d_in[1];
  const float* W_qkv = (const float*)d_in[2];
  const float* b_qkv = (const float*)d_in[3];
  const float* W_ff  = (const float*)d_in[4];
  const float* b_ff  = (const float*)d_in[5];
  float* out = (float*)d_out;

  char* ws = (char*)d_ws;
  _Float16* qkvb = (_Float16*)(ws + OFF_QKV);
  _Float16* msgb = (_Float16*)(ws + OFF_MSG);   // aliases xh (disjoint lifetimes)
  _Float16* xh   = (_Float16*)(ws + OFF_MSG);
  int* srt  = (int*)(ws + OFF_SRT);
  int* deg  = (int*)(ws + OFF_DEG);
  int* offa = (int*)(ws + OFF_OFFA);
  int* cur  = (int*)(ws + OFF_CUR);
  int* flag = (int*)(ws + OFF_FLAG);
  _Float16* wqh = (_Float16*)(ws + OFF_WQH);
  _Float16* wfh = (_Float16*)(ws + OFF_WFH);

  hipMemsetAsync(deg, 0, NN * sizeof(int), stream);
  k_detect64<<<1, 64, 0, stream>>>(edge, flag);

  // f32 -> f16 conversions (x, W_qkv, W_ff)
  k_cvt<<<(NN * DEMB / 8 + 255) / 256, 256, 0, stream>>>(x, xh, NN * DEMB / 8);
  k_cvt<<<(QKV_OUT * DEMB / 8 + 255) / 256, 256, 0, stream>>>(W_qkv, wqh, QKV_OUT * DEMB / 8);
  k_cvt<<<(DEMB * DEMB / 8 + 255) / 256, 256, 0, stream>>>(W_ff, wfh, DEMB * DEMB / 8);

  // QKV projection: [N,512] x [1536,512]^T -> f16 [N,1536]
  k_gemm_nt<true><<<dim3(391, 12), 256, 0, stream>>>(
      xh, wqh, b_qkv, qkvb, NN, QKV_OUT, DEMB);

  k_histo<<<(NE + 255) / 256, 256, 0, stream>>>(edge, flag, deg);
  k_scan<<<1, 1024, 0, stream>>>(deg, offa, cur, NN);
  k_scatter<<<(NE + 255) / 256, 256, 0, stream>>>(edge, flag, cur, srt);

  // per-receiver online softmax + weighted V aggregation -> f16 [N,512]
  k_attn<<<(NN + 3) / 4, 256, 0, stream>>>(qkvb, offa, srt, msgb);

  // output projection: [N,512] x [512,512]^T -> f32 d_out
  k_gemm_nt<false><<<dim3(391, 4), 256, 0, stream>>>(
      msgb, wfh, b_ff, out, NN, DEMB, DEMB);
}